// Round 2
// baseline (3626.390 us; speedup 1.0000x reference)
//
#include <hip/hip_runtime.h>
#include <math.h>

// Problem constants
#define BATCH 32
#define SEQ 256
#define EMBD 256
#define HDIM 256          // per-direction hidden
#define G4H 1024          // 4*H gates per direction
#define TAGS 12
#define START_IDX 10
#define STOP_IDX 11
#define NEGV -10000.0f

// Recurrence weight residency split (in K-value float4 groups, 64 total):
//   registers: groups [0,24)   -> 96 K-values, 384 VGPR/thread
//   LDS      : groups [24,27)  -> 12 K-values, 48 KB
//   L2 stream: groups [27,64)  -> 148 K-values, 592 KB/WG/step
#define KR_G 24
#define KL_G 3
#define KG_G 37

// ---------------- Workspace layout (floats) ----------------
// xg     : [2][8192][1024]            = 16,777,216
// x      : [8192][256]                =  2,097,152
// wpack  : [2][64][1024] float4       =    524,288 floats (full transposed whh)
// h_all  : [32][256][512]             =  4,194,304
// feats  : [32][256][12]              =     98,304
#define WS_XG    0
#define WS_X     16777216
#define WS_WPACK 18874368
#define WS_HALL  19398656
#define WS_FEATS 23592960
// total 23,691,264 floats = 94.8 MB

// ---------------- Kernel 1: gather embeddings ----------------
__global__ void gather_x(const int* __restrict__ sent, const float* __restrict__ emb,
                         float* __restrict__ x) {
    int m = blockIdx.x;            // 8192 positions (b*256+s)
    int lane = threadIdx.x;        // 64
    long long row = sent[m];
    float4 v = *(const float4*)(emb + row * EMBD + lane * 4);
    *(float4*)(x + (size_t)m * EMBD + lane * 4) = v;
}

// ---------------- Kernel 2: transpose whh into [dir][k4][g] float4 pack ----
// pack[dir*65536 + k4*1024 + g] = whh_dir[g][4*k4 .. 4*k4+3]
__global__ void pack_whh(const float* __restrict__ whh_f, const float* __restrict__ whh_b,
                         float4* __restrict__ pack) {
    int idx = blockIdx.x * 256 + threadIdx.x;      // 2*64*1024 = 131072
    if (idx >= 2 * 64 * G4H) return;
    int g = idx & 1023;
    int k4 = (idx >> 10) & 63;
    int dir = idx >> 16;
    const float* w = dir ? whh_b : whh_f;
    pack[idx] = *(const float4*)(w + (size_t)g * HDIM + k4 * 4);
}

// ---------------- Kernel 3: xg GEMM  C[8192][2048] ----------------
__launch_bounds__(256)
__global__ void gemm_xg(const float* __restrict__ x,
                        const float* __restrict__ wih_f, const float* __restrict__ wih_b,
                        const float* __restrict__ bih_f, const float* __restrict__ bhh_f,
                        const float* __restrict__ bih_b, const float* __restrict__ bhh_b,
                        float* __restrict__ xg) {
    __shared__ __align__(16) float as[8][128];
    __shared__ __align__(16) float bs[8][128];
    int m0 = blockIdx.x * 128;     // 64 tiles
    int n0 = blockIdx.y * 128;     // 16 tiles
    int tid = threadIdx.x;
    int tx = tid & 15, ty = tid >> 4;
    int lr = tid >> 1;             // 0..127 tile row
    int lh = (tid & 1) * 4;        // k offset 0 or 4

    const float* arow = x + (size_t)(m0 + lr) * EMBD;
    const float* brow;
    {
        int n = n0 + lr;
        const float* w = (n < G4H) ? wih_f : wih_b;
        brow = w + (size_t)(n & 1023) * EMBD;
    }

    float acc[8][8];
    #pragma unroll
    for (int i = 0; i < 8; i++)
        #pragma unroll
        for (int j = 0; j < 8; j++) acc[i][j] = 0.f;

    for (int k0 = 0; k0 < EMBD; k0 += 8) {
        float4 av = *(const float4*)(arow + k0 + lh);
        float4 bv = *(const float4*)(brow + k0 + lh);
        __syncthreads();
        as[lh + 0][lr] = av.x; as[lh + 1][lr] = av.y; as[lh + 2][lr] = av.z; as[lh + 3][lr] = av.w;
        bs[lh + 0][lr] = bv.x; bs[lh + 1][lr] = bv.y; bs[lh + 2][lr] = bv.z; bs[lh + 3][lr] = bv.w;
        __syncthreads();
        #pragma unroll
        for (int kk = 0; kk < 8; kk++) {
            float4 a0 = *(const float4*)&as[kk][ty * 8];
            float4 a1 = *(const float4*)&as[kk][ty * 8 + 4];
            float4 b0 = *(const float4*)&bs[kk][tx * 8];
            float4 b1 = *(const float4*)&bs[kk][tx * 8 + 4];
            float a[8] = {a0.x, a0.y, a0.z, a0.w, a1.x, a1.y, a1.z, a1.w};
            float b[8] = {b0.x, b0.y, b0.z, b0.w, b1.x, b1.y, b1.z, b1.w};
            #pragma unroll
            for (int i = 0; i < 8; i++)
                #pragma unroll
                for (int j = 0; j < 8; j++) acc[i][j] += a[i] * b[j];
        }
    }

    int n = n0 + tx * 8;
    int dir = n >> 10, g0 = n & 1023;
    const float* bih = dir ? bih_b : bih_f;
    const float* bhh = dir ? bhh_b : bhh_f;
    float bi[8], bh[8];
    #pragma unroll
    for (int j = 0; j < 8; j++) { bi[j] = bih[g0 + j]; bh[j] = bhh[g0 + j]; }
    float* ob = xg + (size_t)dir * 8192 * G4H;
    #pragma unroll
    for (int i = 0; i < 8; i++) {
        int m = m0 + ty * 8 + i;
        float v[8];
        #pragma unroll
        for (int j = 0; j < 8; j++) v[j] = (acc[i][j] + bi[j]) + bh[j];
        *(float4*)(ob + (size_t)m * G4H + g0)     = make_float4(v[0], v[1], v[2], v[3]);
        *(float4*)(ob + (size_t)m * G4H + g0 + 4) = make_float4(v[4], v[5], v[6], v[7]);
    }
}

// ---------------- Kernel 4: LSTM recurrence (v2) ----------------
// One WG (256 threads, 4 waves) per (batch, direction). Thread j owns ALL 4
// gates of hidden unit j -> c stays in a register, one barrier/step via
// double-buffered h in LDS. launch_bounds(256,1): 1 wave/SIMD -> 512 VGPRs.
__launch_bounds__(256, 1)
__global__ void lstm_rec(const float* __restrict__ xg,
                         const float4* __restrict__ wpack,
                         float* __restrict__ h_all) {
    int blk = blockIdx.x;          // 64
    int dir = blk & 1, b = blk >> 1;
    int j = threadIdx.x;           // hidden unit 0..255
    const float4* wp = wpack + (size_t)dir * 64 * G4H;
    const float* xgb = xg + (size_t)dir * 8192 * G4H + (size_t)b * SEQ * G4H;

    __shared__ __align__(16) float hbuf[2][HDIM];   // 2 KB, double-buffered h
    __shared__ __align__(16) float4 wlds[KL_G * G4H]; // 48 KB

    // --- register-resident weights: K-groups [0,24), 4 gates ---
    float4 wr[KR_G][4];
    #pragma unroll
    for (int i = 0; i < KR_G; i++)
        #pragma unroll
        for (int q = 0; q < 4; q++)
            wr[i][q] = wp[i * G4H + (q << 8) + j];

    // --- LDS-resident weights: K-groups [24,27) ---
    for (int i = j; i < KL_G * G4H; i += 256)
        wlds[i] = wp[KR_G * G4H + i];

    const float4* gw = wp + (KR_G + KL_G) * G4H;    // K-groups [27,64)

    float c = 0.f;
    hbuf[0][j] = 0.f;
    __syncthreads();

    // preload xg for first step
    int s0 = dir ? (SEQ - 1) : 0;
    float a0 = xgb[(size_t)s0 * G4H + j];
    float a1 = xgb[(size_t)s0 * G4H + 256 + j];
    float a2 = xgb[(size_t)s0 * G4H + 512 + j];
    float a3 = xgb[(size_t)s0 * G4H + 768 + j];

    for (int t = 0; t < SEQ; t++) {
        int s = dir ? (SEQ - 1 - t) : t;
        const float* hc = hbuf[t & 1];
        float acc0 = a0, acc1 = a1, acc2 = a2, acc3 = a3;

        // prefetch next step's xg (independent of h)
        if (t + 1 < SEQ) {
            int sn = dir ? (SEQ - 2 - t) : (t + 1);
            a0 = xgb[(size_t)sn * G4H + j];
            a1 = xgb[(size_t)sn * G4H + 256 + j];
            a2 = xgb[(size_t)sn * G4H + 512 + j];
            a3 = xgb[(size_t)sn * G4H + 768 + j];
        }

        // registers portion: k 0..95
        #pragma unroll
        for (int k4 = 0; k4 < KR_G; k4++) {
            float4 h4 = *(const float4*)&hc[k4 * 4];
            acc0 += wr[k4][0].x * h4.x + wr[k4][0].y * h4.y + wr[k4][0].z * h4.z + wr[k4][0].w * h4.w;
            acc1 += wr[k4][1].x * h4.x + wr[k4][1].y * h4.y + wr[k4][1].z * h4.z + wr[k4][1].w * h4.w;
            acc2 += wr[k4][2].x * h4.x + wr[k4][2].y * h4.y + wr[k4][2].z * h4.z + wr[k4][2].w * h4.w;
            acc3 += wr[k4][3].x * h4.x + wr[k4][3].y * h4.y + wr[k4][3].z * h4.z + wr[k4][3].w * h4.w;
        }
        // LDS portion: k 96..107
        #pragma unroll
        for (int k4 = 0; k4 < KL_G; k4++) {
            float4 h4 = *(const float4*)&hc[(KR_G + k4) * 4];
            float4 w0 = wlds[k4 * G4H + j];
            float4 w1 = wlds[k4 * G4H + 256 + j];
            float4 w2 = wlds[k4 * G4H + 512 + j];
            float4 w3 = wlds[k4 * G4H + 768 + j];
            acc0 += w0.x * h4.x + w0.y * h4.y + w0.z * h4.z + w0.w * h4.w;
            acc1 += w1.x * h4.x + w1.y * h4.y + w1.z * h4.z + w1.w * h4.w;
            acc2 += w2.x * h4.x + w2.y * h4.y + w2.z * h4.z + w2.w * h4.w;
            acc3 += w3.x * h4.x + w3.y * h4.y + w3.z * h4.z + w3.w * h4.w;
        }
        // L2-streamed portion: k 108..255 (loads independent of h -> pipelinable)
        #pragma unroll 4
        for (int k4 = 0; k4 < KG_G; k4++) {
            float4 h4 = *(const float4*)&hc[(KR_G + KL_G + k4) * 4];
            float4 w0 = gw[(size_t)k4 * G4H + j];
            float4 w1 = gw[(size_t)k4 * G4H + 256 + j];
            float4 w2 = gw[(size_t)k4 * G4H + 512 + j];
            float4 w3 = gw[(size_t)k4 * G4H + 768 + j];
            acc0 += w0.x * h4.x + w0.y * h4.y + w0.z * h4.z + w0.w * h4.w;
            acc1 += w1.x * h4.x + w1.y * h4.y + w1.z * h4.z + w1.w * h4.w;
            acc2 += w2.x * h4.x + w2.y * h4.y + w2.z * h4.z + w2.w * h4.w;
            acc3 += w3.x * h4.x + w3.y * h4.y + w3.z * h4.z + w3.w * h4.w;
        }

        // activation: i,f,g,o = acc0..acc3
        float si = 1.f / (1.f + expf(-acc0));
        float sf = 1.f / (1.f + expf(-acc1));
        float so = 1.f / (1.f + expf(-acc3));
        c = sf * c + si * tanhf(acc2);
        float h = so * tanhf(c);
        hbuf[(t + 1) & 1][j] = h;
        h_all[((size_t)b * SEQ + s) * 512 + dir * HDIM + j] = h;
        __syncthreads();
    }
}

// ---------------- Kernel 5: output projection (feats) ----------------
__global__ void feats_kernel(const float* __restrict__ h_all, const float* __restrict__ w_out,
                             const float* __restrict__ b_out, float* __restrict__ feats) {
    int p = blockIdx.x;            // 8192
    int lane = threadIdx.x;        // 64
    const float* h = h_all + (size_t)p * 512;
    for (int f = 0; f < TAGS; f++) {
        float s = 0.f;
        const float* w = w_out + f * 512;
        #pragma unroll
        for (int k = 0; k < 512; k += 64) s += h[k + lane] * w[k + lane];
        #pragma unroll
        for (int off = 32; off; off >>= 1) s += __shfl_down(s, off);
        if (lane == 0) feats[(size_t)p * TAGS + f] = s + b_out[f];
    }
}

// ---------------- Kernel 6: Viterbi decode ----------------
__global__ void viterbi_kernel(const float* __restrict__ feats, const float* __restrict__ trans,
                               float* __restrict__ out) {
    int b = blockIdx.x;            // 32
    int t = threadIdx.x;           // 64
    __shared__ float fv[TAGS], fvn[TAGS], tr[TAGS * TAGS];
    __shared__ int bp[SEQ][TAGS];  // 12 KB

    for (int i = t; i < TAGS * TAGS; i += 64) tr[i] = trans[i];
    if (t < TAGS) fv[t] = (t == START_IDX) ? 0.f : NEGV;
    __syncthreads();

    const float* fb = feats + (size_t)b * SEQ * TAGS;
    for (int s = 0; s < SEQ; s++) {
        if (t < TAGS) {
            float best = fv[0] + tr[t * TAGS + 0];
            int bi = 0;
            #pragma unroll
            for (int prev = 1; prev < TAGS; prev++) {
                float v = fv[prev] + tr[t * TAGS + prev];
                if (v > best) { best = v; bi = prev; }   // first-index argmax
            }
            bp[s][t] = bi;
            fvn[t] = best + fb[s * TAGS + t];
        }
        __syncthreads();
        if (t < TAGS) fv[t] = fvn[t];
        __syncthreads();
    }

    if (t == 0) {
        float best = fv[0] + tr[STOP_IDX * TAGS + 0];
        int bi = 0;
        #pragma unroll
        for (int p = 1; p < TAGS; p++) {
            float v = fv[p] + tr[STOP_IDX * TAGS + p];
            if (v > best) { best = v; bi = p; }
        }
        out[b] = best;                                   // score
        float* path = out + BATCH + (size_t)b * SEQ;
        int tag = bi;
        path[SEQ - 1] = (float)tag;
        for (int s = SEQ - 1; s >= 1; s--) {
            tag = bp[s][tag];
            path[s - 1] = (float)tag;
        }
    }
}

// ---------------- Launch ----------------
extern "C" void kernel_launch(void* const* d_in, const int* in_sizes, int n_in,
                              void* d_out, int out_size, void* d_ws, size_t ws_size,
                              hipStream_t stream) {
    const int*   sent  = (const int*)d_in[0];
    const float* emb   = (const float*)d_in[1];
    const float* wih_f = (const float*)d_in[2];
    const float* whh_f = (const float*)d_in[3];
    const float* bih_f = (const float*)d_in[4];
    const float* bhh_f = (const float*)d_in[5];
    const float* wih_b = (const float*)d_in[6];
    const float* whh_b = (const float*)d_in[7];
    const float* bih_b = (const float*)d_in[8];
    const float* bhh_b = (const float*)d_in[9];
    const float* w_out = (const float*)d_in[10];
    const float* b_out = (const float*)d_in[11];
    const float* trans = (const float*)d_in[12];
    float* ws    = (float*)d_ws;
    float* xg    = ws + WS_XG;
    float* x     = ws + WS_X;
    float* wpack = ws + WS_WPACK;
    float* h_all = ws + WS_HALL;
    float* feats = ws + WS_FEATS;
    float* out   = (float*)d_out;

    gather_x<<<BATCH * SEQ, 64, 0, stream>>>(sent, emb, x);
    pack_whh<<<(2 * 64 * G4H + 255) / 256, 256, 0, stream>>>(whh_f, whh_b, (float4*)wpack);
    gemm_xg<<<dim3(64, 16), 256, 0, stream>>>(x, wih_f, wih_b, bih_f, bhh_f, bih_b, bhh_b, xg);
    lstm_rec<<<64, 256, 0, stream>>>(xg, (const float4*)wpack, h_all);
    feats_kernel<<<BATCH * SEQ, 64, 0, stream>>>(h_all, w_out, b_out, feats);
    viterbi_kernel<<<BATCH, 64, 0, stream>>>(feats, trans, out);
}

// Round 3
// 1981.080 us; speedup vs baseline: 1.8305x; 1.8305x over previous
//
#include <hip/hip_runtime.h>
#include <math.h>

// Problem constants
#define BATCH 32
#define SEQ 256
#define EMBD 256
#define HDIM 256          // per-direction hidden
#define G4H 1024          // 4*H gates per direction
#define TAGS 12
#define START_IDX 10
#define STOP_IDX 11
#define NEGV -10000.0f

// Recurrence weight residency (float4 K-groups, 64 total), per thread-gate:
//   registers: groups [0,16)   -> 64 floats/thread (under the 256-VGPR ISA cap
//                                 with 128-VGPR occupancy budget at 4 waves/SIMD)
//   LDS      : groups [16,19)  -> 48 KB static
//   L2 stream: groups [19,64)  -> 45 groups = 720 KB/WG/step
#define KRG 16
#define KLG 3
#define KSG 45

// ---------------- Workspace layout (floats) ----------------
#define WS_XG    0              // xg   [2][8192][1024]
#define WS_X     16777216       // x    [8192][256]
#define WS_WPACK 18874368       // wpack[2][64][1024] float4
#define WS_HALL  19398656       // h_all[32][256][512]
#define WS_FEATS 23592960       // feats[32][256][12]

// ---------------- Kernel 1: gather embeddings ----------------
__global__ void gather_x(const int* __restrict__ sent, const float* __restrict__ emb,
                         float* __restrict__ x) {
    int m = blockIdx.x;            // 8192 positions (b*256+s)
    int lane = threadIdx.x;        // 64
    long long row = sent[m];
    float4 v = *(const float4*)(emb + row * EMBD + lane * 4);
    *(float4*)(x + (size_t)m * EMBD + lane * 4) = v;
}

// ---------------- Kernel 2: transpose whh into [dir][k4][g] float4 pack ----
__global__ void pack_whh(const float* __restrict__ whh_f, const float* __restrict__ whh_b,
                         float4* __restrict__ pack) {
    int idx = blockIdx.x * 256 + threadIdx.x;      // 2*64*1024 = 131072
    if (idx >= 2 * 64 * G4H) return;
    int g = idx & 1023;
    int k4 = (idx >> 10) & 63;
    int dir = idx >> 16;
    const float* w = dir ? whh_b : whh_f;
    pack[idx] = *(const float4*)(w + (size_t)g * HDIM + k4 * 4);
}

// ---------------- Kernel 3: xg GEMM  C[8192][2048] ----------------
__launch_bounds__(256)
__global__ void gemm_xg(const float* __restrict__ x,
                        const float* __restrict__ wih_f, const float* __restrict__ wih_b,
                        const float* __restrict__ bih_f, const float* __restrict__ bhh_f,
                        const float* __restrict__ bih_b, const float* __restrict__ bhh_b,
                        float* __restrict__ xg) {
    __shared__ __align__(16) float as[8][128];
    __shared__ __align__(16) float bs[8][128];
    int m0 = blockIdx.x * 128;     // 64 tiles
    int n0 = blockIdx.y * 128;     // 16 tiles
    int tid = threadIdx.x;
    int tx = tid & 15, ty = tid >> 4;
    int lr = tid >> 1;             // 0..127 tile row
    int lh = (tid & 1) * 4;        // k offset 0 or 4

    const float* arow = x + (size_t)(m0 + lr) * EMBD;
    const float* brow;
    {
        int n = n0 + lr;
        const float* w = (n < G4H) ? wih_f : wih_b;
        brow = w + (size_t)(n & 1023) * EMBD;
    }

    float acc[8][8];
    #pragma unroll
    for (int i = 0; i < 8; i++)
        #pragma unroll
        for (int j = 0; j < 8; j++) acc[i][j] = 0.f;

    for (int k0 = 0; k0 < EMBD; k0 += 8) {
        float4 av = *(const float4*)(arow + k0 + lh);
        float4 bv = *(const float4*)(brow + k0 + lh);
        __syncthreads();
        as[lh + 0][lr] = av.x; as[lh + 1][lr] = av.y; as[lh + 2][lr] = av.z; as[lh + 3][lr] = av.w;
        bs[lh + 0][lr] = bv.x; bs[lh + 1][lr] = bv.y; bs[lh + 2][lr] = bv.z; bs[lh + 3][lr] = bv.w;
        __syncthreads();
        #pragma unroll
        for (int kk = 0; kk < 8; kk++) {
            float4 a0 = *(const float4*)&as[kk][ty * 8];
            float4 a1 = *(const float4*)&as[kk][ty * 8 + 4];
            float4 b0 = *(const float4*)&bs[kk][tx * 8];
            float4 b1 = *(const float4*)&bs[kk][tx * 8 + 4];
            float a[8] = {a0.x, a0.y, a0.z, a0.w, a1.x, a1.y, a1.z, a1.w};
            float b[8] = {b0.x, b0.y, b0.z, b0.w, b1.x, b1.y, b1.z, b1.w};
            #pragma unroll
            for (int i = 0; i < 8; i++)
                #pragma unroll
                for (int j = 0; j < 8; j++) acc[i][j] += a[i] * b[j];
        }
    }

    int n = n0 + tx * 8;
    int dir = n >> 10, g0 = n & 1023;
    const float* bih = dir ? bih_b : bih_f;
    const float* bhh = dir ? bhh_b : bhh_f;
    float bi[8], bh[8];
    #pragma unroll
    for (int j = 0; j < 8; j++) { bi[j] = bih[g0 + j]; bh[j] = bhh[g0 + j]; }
    float* ob = xg + (size_t)dir * 8192 * G4H;
    #pragma unroll
    for (int i = 0; i < 8; i++) {
        int m = m0 + ty * 8 + i;
        float v[8];
        #pragma unroll
        for (int j = 0; j < 8; j++) v[j] = (acc[i][j] + bi[j]) + bh[j];
        *(float4*)(ob + (size_t)m * G4H + g0)     = make_float4(v[0], v[1], v[2], v[3]);
        *(float4*)(ob + (size_t)m * G4H + g0 + 4) = make_float4(v[4], v[5], v[6], v[7]);
    }
}

// ---------------- Kernel 4: LSTM recurrence (v3) ----------------
// 64 WGs (one per batch,dir) x 1024 threads; thread g owns gate g.
// launch_bounds(1024,4): 16 waves/WG, 4 waves/SIMD -> 128-VGPR budget.
// 64 weight floats/thread in regs (NO spill), 3 K-groups in LDS, 45 streamed
// from L2 with unroll-5 for MLP. 2 barriers/step.
__launch_bounds__(1024, 4)
__global__ void lstm_rec(const float* __restrict__ xg,
                         const float4* __restrict__ wpack,
                         float* __restrict__ h_all) {
    int blk = blockIdx.x;          // 64
    int dir = blk & 1, b = blk >> 1;
    int g = threadIdx.x;           // gate 0..1023
    const float4* wp = wpack + (size_t)dir * 64 * G4H;
    const float* xgb = xg + (size_t)dir * 8192 * G4H + (size_t)b * SEQ * G4H;

    __shared__ __align__(16) float hbuf[2][HDIM];     // 2 KB
    __shared__ float gates[G4H];                      // 4 KB
    __shared__ __align__(16) float4 wlds[KLG * G4H];  // 48 KB

    // register-resident weights: K-groups [0,16) of this gate's row
    float4 wr[KRG];
    #pragma unroll
    for (int i = 0; i < KRG; i++) wr[i] = wp[i * G4H + g];

    // LDS-resident weights: K-groups [16,19)
    for (int i = g; i < KLG * G4H; i += 1024) wlds[i] = wp[KRG * G4H + i];

    const float4* gw = wp + (KRG + KLG) * G4H;        // streamed K-groups [19,64)

    float c = 0.f;
    if (g < HDIM) hbuf[0][g] = 0.f;
    __syncthreads();

    int s0 = dir ? (SEQ - 1) : 0;
    float xnext = xgb[(size_t)s0 * G4H + g];

    for (int t = 0; t < SEQ; t++) {
        int s = dir ? (SEQ - 1 - t) : t;
        const float* hc = hbuf[t & 1];
        float acc = xnext;

        // prefetch next step's xg (h-independent)
        if (t + 1 < SEQ) {
            int sn = dir ? (SEQ - 2 - t) : (t + 1);
            xnext = xgb[(size_t)sn * G4H + g];
        }

        // register portion: k 0..63
        #pragma unroll
        for (int k4 = 0; k4 < KRG; k4++) {
            float4 h4 = *(const float4*)&hc[k4 * 4];
            acc += wr[k4].x * h4.x + wr[k4].y * h4.y + wr[k4].z * h4.z + wr[k4].w * h4.w;
        }
        // LDS portion: k 64..75
        #pragma unroll
        for (int k4 = 0; k4 < KLG; k4++) {
            float4 h4 = *(const float4*)&hc[(KRG + k4) * 4];
            float4 w4 = wlds[k4 * G4H + g];
            acc += w4.x * h4.x + w4.y * h4.y + w4.z * h4.z + w4.w * h4.w;
        }
        // L2-streamed portion: k 76..255; unroll 5 -> ~5 outstanding wave-loads
        #pragma unroll 5
        for (int k4 = 0; k4 < KSG; k4++) {
            float4 h4 = *(const float4*)&hc[(KRG + KLG + k4) * 4];
            float4 w4 = gw[(size_t)k4 * G4H + g];
            acc += w4.x * h4.x + w4.y * h4.y + w4.z * h4.z + w4.w * h4.w;
        }

        gates[g] = acc;
        __syncthreads();
        if (g < HDIM) {
            float gi = gates[g], gf = gates[HDIM + g], gg = gates[2 * HDIM + g], go = gates[3 * HDIM + g];
            float si = 1.f / (1.f + expf(-gi));
            float sf = 1.f / (1.f + expf(-gf));
            float so = 1.f / (1.f + expf(-go));
            c = sf * c + si * tanhf(gg);
            float h = so * tanhf(c);
            hbuf[(t + 1) & 1][g] = h;
            h_all[((size_t)b * SEQ + s) * 512 + dir * HDIM + g] = h;
        }
        __syncthreads();
    }
}

// ---------------- Kernel 5: output projection (feats) ----------------
__global__ void feats_kernel(const float* __restrict__ h_all, const float* __restrict__ w_out,
                             const float* __restrict__ b_out, float* __restrict__ feats) {
    int p = blockIdx.x;            // 8192
    int lane = threadIdx.x;        // 64
    const float* h = h_all + (size_t)p * 512;
    for (int f = 0; f < TAGS; f++) {
        float s = 0.f;
        const float* w = w_out + f * 512;
        #pragma unroll
        for (int k = 0; k < 512; k += 64) s += h[k + lane] * w[k + lane];
        #pragma unroll
        for (int off = 32; off; off >>= 1) s += __shfl_down(s, off);
        if (lane == 0) feats[(size_t)p * TAGS + f] = s + b_out[f];
    }
}

// ---------------- Kernel 6: Viterbi decode ----------------
__global__ void viterbi_kernel(const float* __restrict__ feats, const float* __restrict__ trans,
                               float* __restrict__ out) {
    int b = blockIdx.x;            // 32
    int t = threadIdx.x;           // 64
    __shared__ float fv[TAGS], fvn[TAGS], tr[TAGS * TAGS];
    __shared__ int bp[SEQ][TAGS];  // 12 KB

    for (int i = t; i < TAGS * TAGS; i += 64) tr[i] = trans[i];
    if (t < TAGS) fv[t] = (t == START_IDX) ? 0.f : NEGV;
    __syncthreads();

    const float* fb = feats + (size_t)b * SEQ * TAGS;
    for (int s = 0; s < SEQ; s++) {
        if (t < TAGS) {
            float best = fv[0] + tr[t * TAGS + 0];
            int bi = 0;
            #pragma unroll
            for (int prev = 1; prev < TAGS; prev++) {
                float v = fv[prev] + tr[t * TAGS + prev];
                if (v > best) { best = v; bi = prev; }   // first-index argmax
            }
            bp[s][t] = bi;
            fvn[t] = best + fb[s * TAGS + t];
        }
        __syncthreads();
        if (t < TAGS) fv[t] = fvn[t];
        __syncthreads();
    }

    if (t == 0) {
        float best = fv[0] + tr[STOP_IDX * TAGS + 0];
        int bi = 0;
        #pragma unroll
        for (int p = 1; p < TAGS; p++) {
            float v = fv[p] + tr[STOP_IDX * TAGS + p];
            if (v > best) { best = v; bi = p; }
        }
        out[b] = best;                                   // score
        float* path = out + BATCH + (size_t)b * SEQ;
        int tag = bi;
        path[SEQ - 1] = (float)tag;
        for (int s = SEQ - 1; s >= 1; s--) {
            tag = bp[s][tag];
            path[s - 1] = (float)tag;
        }
    }
}

// ---------------- Launch ----------------
extern "C" void kernel_launch(void* const* d_in, const int* in_sizes, int n_in,
                              void* d_out, int out_size, void* d_ws, size_t ws_size,
                              hipStream_t stream) {
    const int*   sent  = (const int*)d_in[0];
    const float* emb   = (const float*)d_in[1];
    const float* wih_f = (const float*)d_in[2];
    const float* whh_f = (const float*)d_in[3];
    const float* bih_f = (const float*)d_in[4];
    const float* bhh_f = (const float*)d_in[5];
    const float* wih_b = (const float*)d_in[6];
    const float* whh_b = (const float*)d_in[7];
    const float* bih_b = (const float*)d_in[8];
    const float* bhh_b = (const float*)d_in[9];
    const float* w_out = (const float*)d_in[10];
    const float* b_out = (const float*)d_in[11];
    const float* trans = (const float*)d_in[12];
    float* ws    = (float*)d_ws;
    float* xg    = ws + WS_XG;
    float* x     = ws + WS_X;
    float* wpack = ws + WS_WPACK;
    float* h_all = ws + WS_HALL;
    float* feats = ws + WS_FEATS;
    float* out   = (float*)d_out;

    gather_x<<<BATCH * SEQ, 64, 0, stream>>>(sent, emb, x);
    pack_whh<<<(2 * 64 * G4H + 255) / 256, 256, 0, stream>>>(whh_f, whh_b, (float4*)wpack);
    gemm_xg<<<dim3(64, 16), 256, 0, stream>>>(x, wih_f, wih_b, bih_f, bhh_f, bih_b, bhh_b, xg);
    lstm_rec<<<64, 1024, 0, stream>>>(xg, (const float4*)wpack, h_all);
    feats_kernel<<<BATCH * SEQ, 64, 0, stream>>>(h_all, w_out, b_out, feats);
    viterbi_kernel<<<BATCH, 64, 0, stream>>>(feats, trans, out);
}